// Round 2
// baseline (353.890 us; speedup 1.0000x reference)
//
#include <hip/hip_runtime.h>
#include <stdint.h>

// B=16, C=64, H=128, W=128, HX=HY=64. All I/O fp32.
// Pipeline (3 kernels):
//   k_proj0 : pre_x[t=w][seq=(b,h)][j] (f16, incl bias) = Wihx·x + b
//   k_scan<0>: X recurrence; FUSED Y-projection -> pre_y[t=h][seq=(b,w)][j] (f16, incl bias)
//   k_scan<1>: Y recurrence -> out[b][j][h][w] fp32
// d_ws: pre_x (33.5MB) + pre_y (33.5MB) = 67MB. No out_x staging at all.
// Scan design: barrier-per-step for cross-wave h exchange. ALL global memory
// ops are batched once per GT-step group (reg-slab loads + reg-staged store
// bursts) so most __syncthreads have no outstanding vmem to drain.
// ROUND 2: DUAL-CHAIN ILP. Each 256-thr block owns TWO independent 16-seq
// chains (c=0,1). Both chains' MFMAs/tanh/LDS ops live in the same
// straight-line region between barriers -> the compiler interleaves them and
// each chain's latency stalls are filled by the other chain's instructions.
// One barrier serves 2 chain-steps. NO launch_bounds min-waves arg (round-1
// lesson: it capped VGPR to 100 and spilled the slab to scratch). GT=8 keeps
// live state ~200 VGPR.

#define TLEN 128
#define NSEQ 2048
#define PSH (NSEQ*64)   // f16 elems per t-slice
#define GT 8            // steps per group

typedef __bf16   bf16x8 __attribute__((ext_vector_type(8)));
typedef _Float16 f16x4  __attribute__((ext_vector_type(4)));
typedef float    f32x4  __attribute__((ext_vector_type(4)));
typedef unsigned short u16x4 __attribute__((ext_vector_type(4)));

static __device__ __forceinline__ unsigned int fbits(float f){
    union { float f; unsigned int u; } v; v.f = f; return v.u;
}
static __device__ __forceinline__ float ubits(unsigned int u){
    union { unsigned int u; float f; } v; v.u = u; return v.f;
}
static __device__ __forceinline__ float bf2f(unsigned short s){ return ubits(((unsigned int)s) << 16); }
static __device__ __forceinline__ unsigned short f2bf(float f){
    unsigned int u = fbits(f);
    return (unsigned short)((u + 0x7FFFu + ((u >> 16) & 1u)) >> 16);
}
static __device__ __forceinline__ __bf16 us2b(unsigned short s){
    union { unsigned short u; __bf16 b; } v; v.u = s; return v.b;
}
struct bfpair { __bf16 hi, lo; };
static __device__ __forceinline__ bfpair splitf(float f){   // RNE split (weights, once)
    unsigned short h = f2bf(f);
    bfpair r; r.hi = us2b(h); r.lo = us2b(f2bf(f - bf2f(h))); return r;
}
static __device__ __forceinline__ float fast_tanh(float x){
    float e = __builtin_amdgcn_exp2f(x * 2.8853900817779268f);
    return 1.0f - 2.0f * __builtin_amdgcn_rcpf(e + 1.0f);
}

// ---------------------------------------------------------------------------
// k_proj0: pre_x[w][b*128+h][j] = f16( sum_c x[b][c][h][w]*Wihx[j][c] + bias )
// bf16 hi/lo 3-term MFMA. Block 256thr/4 waves; wave: 32 rows x 64 j.
__global__ __launch_bounds__(256) void k_proj0(const float* __restrict__ A,
                                               const float* __restrict__ Wih,
                                               const float* __restrict__ b1,
                                               const float* __restrict__ b2,
                                               _Float16* __restrict__ pre){
    int lane = threadIdx.x & 63;
    int wv   = threadIdx.x >> 6;
    int q    = lane >> 4, l15 = lane & 15;

    bf16x8 Whi[4][2], Wlo[4][2];
#pragma unroll
    for (int n = 0; n < 4; n++)
#pragma unroll
        for (int kc = 0; kc < 2; kc++){
            const float* p = Wih + (n * 16 + l15) * 64 + kc * 32 + q * 8;
#pragma unroll
            for (int i = 0; i < 8; i++){
                bfpair s = splitf(p[i]);
                Whi[n][kc][i] = s.hi; Wlo[n][kc][i] = s.lo;
            }
        }
    float bias[4];
#pragma unroll
    for (int n = 0; n < 4; n++){
        int j = n * 16 + l15;
        bias[n] = b1[j] + b2[j];
    }

    int row0 = blockIdx.x * 128 + wv * 32;

    float av[2][2][8];
#pragma unroll
    for (int mi = 0; mi < 2; mi++){
        int r = row0 + mi * 16 + l15;
        int b = r >> 14, hw = r & 16383;
        const float* xb = A + (size_t)b * 1048576 + hw;
#pragma unroll
        for (int kc = 0; kc < 2; kc++)
#pragma unroll
            for (int i = 0; i < 8; i++)
                av[mi][kc][i] = xb[(size_t)(kc * 32 + q * 8 + i) * 16384];
    }

#pragma unroll
    for (int mi = 0; mi < 2; mi++){
        int rb = row0 + mi * 16;
        bf16x8 Ahi[2], Alo[2];
#pragma unroll
        for (int kc = 0; kc < 2; kc++)
#pragma unroll
            for (int i = 0; i < 8; i++){
                bfpair s = splitf(av[mi][kc][i]);
                Ahi[kc][i] = s.hi; Alo[kc][i] = s.lo;
            }
        f32x4 acc[4];
#pragma unroll
        for (int n = 0; n < 4; n++) acc[n] = (f32x4){bias[n], bias[n], bias[n], bias[n]};
#pragma unroll
        for (int n = 0; n < 4; n++)
#pragma unroll
            for (int kc = 0; kc < 2; kc++){
                acc[n] = __builtin_amdgcn_mfma_f32_16x16x32_bf16(Ahi[kc], Whi[n][kc], acc[n], 0, 0, 0);
                acc[n] = __builtin_amdgcn_mfma_f32_16x16x32_bf16(Alo[kc], Whi[n][kc], acc[n], 0, 0, 0);
                acc[n] = __builtin_amdgcn_mfma_f32_16x16x32_bf16(Ahi[kc], Wlo[n][kc], acc[n], 0, 0, 0);
            }
        // rows rb..rb+15 share (b,h); w = (rb&127) + q*4 + rr. seq_x = b*128+h.
        int bT = rb >> 14, hT = (rb >> 7) & 127, wBase = rb & 127;
        size_t seqOff = (size_t)bT * 128 + hT;
#pragma unroll
        for (int n = 0; n < 4; n++)
#pragma unroll
            for (int rr = 0; rr < 4; rr++){
                int w = wBase + q * 4 + rr;
                pre[((size_t)w * NSEQ + seqOff) * 64 + n * 16 + l15] = (_Float16)acc[n][rr];
            }
    }
}

// ---------------------------------------------------------------------------
// k_scan<PASS>: h_t = tanh(pre_t + Whh h_{t-1}), 64 blocks x 4 waves.
// Each block: TWO independent chains (c=0: seqs n0..n0+15, c=1: +16..+31).
// Wave wv owns j-tile [wv*16,+16) for BOTH chains. Whh hi/lo pinned in VGPRs.
// h exchanged via swizzled LDS (parity dbuf, per-chain region) + one
// __syncthreads per step serving both chains. pre slab (GT steps x 2 chains)
// loaded into registers at group top; outputs staged in registers and
// burst-stored at group end -> barriers stay vmcnt-clean.
// PASS 0: fused Y-proj on B-frags (h_{t-1}) -> pre_y[t-1] f16 (incl bias_y).
// PASS 1: final out[b][j][t][w] fp32.
template<int PASS>
__global__ __launch_bounds__(256) void k_scan(const _Float16* __restrict__ pre,
                                              const float* __restrict__ Whh,
                                              const float* __restrict__ Wy,
                                              const float* __restrict__ by1,
                                              const float* __restrict__ by2,
                                              _Float16* __restrict__ prey,
                                              float* __restrict__ outf){
    __shared__ alignas(16) unsigned short hbuf[2][2][2][16][64];  // [chain][par][hi/lo]
    int lane = threadIdx.x & 63;
    int wv   = threadIdx.x >> 6;
    int q = lane >> 4, l15 = lane & 15;
    int n0 = blockIdx.x * 32;
    int j0 = wv * 16 + q * 4;

    bf16x8 Ahi[2], Alo[2];
#pragma unroll
    for (int kc = 0; kc < 2; kc++){
        const float* p = Whh + (wv * 16 + l15) * 64 + kc * 32 + q * 8;
#pragma unroll
        for (int i = 0; i < 8; i++){
            bfpair s = splitf(p[i]);
            Ahi[kc][i] = s.hi; Alo[kc][i] = s.lo;
        }
    }
    bf16x8 Yhi[2], Ylo[2];
    f32x4  biasy = (f32x4){0.f, 0.f, 0.f, 0.f};
    if constexpr (PASS == 0){
#pragma unroll
        for (int kc = 0; kc < 2; kc++){
            const float* p = Wy + (wv * 16 + l15) * 64 + kc * 32 + q * 8;
#pragma unroll
            for (int i = 0; i < 8; i++){
                bfpair s = splitf(p[i]);
                Yhi[kc][i] = s.hi; Ylo[kc][i] = s.lo;
            }
        }
#pragma unroll
        for (int r = 0; r < 4; r++) biasy[r] = by1[j0 + r] + by2[j0 + r];
    }

    bf16x8 Bhi[2][2], Blo[2][2];   // [chain][kc]
#pragma unroll
    for (int c = 0; c < 2; c++)
#pragma unroll
        for (int kc = 0; kc < 2; kc++)
#pragma unroll
            for (int i = 0; i < 8; i++){ Bhi[c][kc][i] = us2b(0); Blo[c][kc][i] = us2b(0); }

    int bb = n0 >> 7, low7 = n0 & 127;   // chains share bb; chain c: low7+c*16

    const _Float16* pb[2];
    size_t spy[2];
#pragma unroll
    for (int c = 0; c < 2; c++){
        pb[c]  = pre + (size_t)(n0 + c * 16 + l15) * 64 + j0;
        spy[c] = (size_t)(low7 + c * 16 + l15) * NSEQ + (size_t)bb * 128;
    }

    int e   = l15 & 7;
    int wj  = (((j0 >> 3) ^ e) << 3) | (j0 & 7);
    int rj0 = ((q)     ^ e) << 3;
    int rj1 = ((4 + q) ^ e) << 3;

    f16x4 ps[2][GT];
    u16x4 prey_st[2][GT];
    f32x4 outst[2][GT];

    for (int g = 0; g < TLEN / GT; g++){
        int G = g * GT;
#pragma unroll
        for (int c = 0; c < 2; c++)
#pragma unroll
            for (int u = 0; u < GT; u++)
                ps[c][u] = *(const f16x4*)(pb[c] + (size_t)(G + u) * PSH);

#pragma unroll
        for (int u = 0; u < GT; u++){
            int t = G + u;
            int par = t & 1;
            // ---- both chains' work in one straight-line region: the
            //      compiler interleaves c=0 and c=1 (fully independent) so
            //      each chain's MFMA/tanh/LDS latency hides under the other.
#pragma unroll
            for (int c = 0; c < 2; c++){
                // recurrence MFMAs (critical path)
                f32x4 a0 = (f32x4){(float)ps[c][u][0], (float)ps[c][u][1],
                                   (float)ps[c][u][2], (float)ps[c][u][3]};
                f32x4 a1 = (f32x4){0.f, 0.f, 0.f, 0.f};
                f32x4 a2 = (f32x4){0.f, 0.f, 0.f, 0.f};
                a0 = __builtin_amdgcn_mfma_f32_16x16x32_bf16(Ahi[0], Bhi[c][0], a0, 0, 0, 0);
                a1 = __builtin_amdgcn_mfma_f32_16x16x32_bf16(Ahi[0], Blo[c][0], a1, 0, 0, 0);
                a2 = __builtin_amdgcn_mfma_f32_16x16x32_bf16(Alo[0], Bhi[c][0], a2, 0, 0, 0);
                a0 = __builtin_amdgcn_mfma_f32_16x16x32_bf16(Ahi[1], Bhi[c][1], a0, 0, 0, 0);
                a1 = __builtin_amdgcn_mfma_f32_16x16x32_bf16(Ahi[1], Blo[c][1], a1, 0, 0, 0);
                a2 = __builtin_amdgcn_mfma_f32_16x16x32_bf16(Alo[1], Bhi[c][1], a2, 0, 0, 0);
                // fused Y-proj on current B (= h_{t-1}) -> pre_y[t-1]
                if constexpr (PASS == 0){
                    f32x4 y0 = biasy;
                    f32x4 y1 = (f32x4){0.f, 0.f, 0.f, 0.f};
                    y0 = __builtin_amdgcn_mfma_f32_16x16x32_bf16(Yhi[0], Bhi[c][0], y0, 0, 0, 0);
                    y0 = __builtin_amdgcn_mfma_f32_16x16x32_bf16(Yhi[1], Bhi[c][1], y0, 0, 0, 0);
                    y1 = __builtin_amdgcn_mfma_f32_16x16x32_bf16(Ylo[0], Bhi[c][0], y1, 0, 0, 0);
                    y1 = __builtin_amdgcn_mfma_f32_16x16x32_bf16(Ylo[1], Bhi[c][1], y1, 0, 0, 0);
                    y1 = __builtin_amdgcn_mfma_f32_16x16x32_bf16(Yhi[0], Blo[c][0], y1, 0, 0, 0);
                    y1 = __builtin_amdgcn_mfma_f32_16x16x32_bf16(Yhi[1], Blo[c][1], y1, 0, 0, 0);
                    f32x4 ys = y0 + y1;
#pragma unroll
                    for (int r = 0; r < 4; r++){
                        union { _Float16 h; unsigned short s; } cv;
                        cv.h = (_Float16)ys[r];
                        prey_st[c][u][r] = cv.s;
                    }
                }
                f32x4 acc = (a0 + a1) + a2;

                u16x4 hi4, lo4;
#pragma unroll
                for (int r = 0; r < 4; r++){
                    float tv = fast_tanh(acc[r]);
                    if constexpr (PASS == 1) outst[c][u][r] = tv;
                    unsigned int ub = fbits(tv);
                    hi4[r] = (unsigned short)(ub >> 16);          // trunc-bf16 hi
                    float lof = tv - ubits(ub & 0xFFFF0000u);     // exact remainder
                    lo4[r] = (unsigned short)(fbits(lof) >> 16);  // trunc-bf16 lo
                }
                *(u16x4*)&hbuf[c][par][0][l15][wj] = hi4;
                *(u16x4*)&hbuf[c][par][1][l15][wj] = lo4;
            }
            __syncthreads();
#pragma unroll
            for (int c = 0; c < 2; c++){
                Bhi[c][0] = *(const bf16x8*)&hbuf[c][par][0][l15][rj0];
                Blo[c][0] = *(const bf16x8*)&hbuf[c][par][1][l15][rj0];
                Bhi[c][1] = *(const bf16x8*)&hbuf[c][par][0][l15][rj1];
                Blo[c][1] = *(const bf16x8*)&hbuf[c][par][1][l15][rj1];
            }
        }
        // ---- burst stores (drained once at next group's first barrier)
        if constexpr (PASS == 0){
#pragma unroll
            for (int c = 0; c < 2; c++)
#pragma unroll
                for (int u = 0; u < GT; u++){
                    int tp = G - 1 + u;
                    if (tp >= 0)
                        *(u16x4*)(prey + (spy[c] + tp) * 64 + j0) = prey_st[c][u];
                }
        } else {
#pragma unroll
            for (int c = 0; c < 2; c++)
#pragma unroll
                for (int u = 0; u < GT; u++)
#pragma unroll
                    for (int r = 0; r < 4; r++)
                        outf[((size_t)(bb * 64 + j0 + r) * TLEN + (G + u)) * 128
                             + low7 + c * 16 + l15] = outst[c][u][r];
        }
    }
    // tail: pre_y[127] from final B (= h_127), both chains
    if constexpr (PASS == 0){
#pragma unroll
        for (int c = 0; c < 2; c++){
            f32x4 y0 = biasy;
            f32x4 y1 = (f32x4){0.f, 0.f, 0.f, 0.f};
            y0 = __builtin_amdgcn_mfma_f32_16x16x32_bf16(Yhi[0], Bhi[c][0], y0, 0, 0, 0);
            y0 = __builtin_amdgcn_mfma_f32_16x16x32_bf16(Yhi[1], Bhi[c][1], y0, 0, 0, 0);
            y1 = __builtin_amdgcn_mfma_f32_16x16x32_bf16(Ylo[0], Bhi[c][0], y1, 0, 0, 0);
            y1 = __builtin_amdgcn_mfma_f32_16x16x32_bf16(Ylo[1], Bhi[c][1], y1, 0, 0, 0);
            y1 = __builtin_amdgcn_mfma_f32_16x16x32_bf16(Yhi[0], Blo[c][0], y1, 0, 0, 0);
            y1 = __builtin_amdgcn_mfma_f32_16x16x32_bf16(Yhi[1], Blo[c][1], y1, 0, 0, 0);
            f32x4 ys = y0 + y1;
            u16x4 pv;
#pragma unroll
            for (int r = 0; r < 4; r++){
                union { _Float16 h; unsigned short s; } cv;
                cv.h = (_Float16)ys[r];
                pv[r] = cv.s;
            }
            *(u16x4*)(prey + (spy[c] + (TLEN - 1)) * 64 + j0) = pv;
        }
    }
}

// ---------------------------------------------------------------------------
extern "C" void kernel_launch(void* const* d_in, const int* in_sizes, int n_in,
                              void* d_out, int out_size, void* d_ws, size_t ws_size,
                              hipStream_t stream){
    (void)in_sizes; (void)n_in; (void)out_size; (void)ws_size;
    const float* x    = (const float*)d_in[0];
    const float* Wihx = (const float*)d_in[1];
    const float* Whhx = (const float*)d_in[2];
    const float* bihx = (const float*)d_in[3];
    const float* bhhx = (const float*)d_in[4];
    const float* Wihy = (const float*)d_in[5];
    const float* Whhy = (const float*)d_in[6];
    const float* bihy = (const float*)d_in[7];
    const float* bhhy = (const float*)d_in[8];
    _Float16* prex = (_Float16*)d_ws;                          // 33.5MB
    _Float16* prey = prex + (size_t)NSEQ * TLEN * 64;          // 33.5MB
    float* of = (float*)d_out;

    k_proj0 <<<2048, 256, 0, stream>>>(x, Wihx, bihx, bhhx, prex);
    k_scan<0><<<64, 256, 0, stream>>>(prex, Whhx, Wihy, bihy, bhhy, prey, nullptr);
    k_scan<1><<<64, 256, 0, stream>>>(prey, Whhy, nullptr, nullptr, nullptr, nullptr, of);
}

// Round 3
// 337.701 us; speedup vs baseline: 1.0479x; 1.0479x over previous
//
#include <hip/hip_runtime.h>
#include <stdint.h>

// B=16, C=64, H=128, W=128, HX=HY=64. All I/O fp32.
// Pipeline (3 kernels):
//   k_proj0 : pre_x[t=w][seq=(b,h)][j] (f16, incl bias) = Wihx·x + b
//   k_scan<0>: X recurrence; FUSED Y-projection -> pre_y[t=h][seq=(b,w)][j] (f16, incl bias)
//   k_scan<1>: Y recurrence -> out[b][j][h][w] fp32
// d_ws: pre_x (33.5MB) + pre_y (33.5MB) = 67MB. No out_x staging at all.
// Scan design: barrier-per-step for cross-wave h exchange. ALL global memory
// ops are batched once per 16-step group (reg-slab loads + reg-staged store
// bursts) so 15/16 __syncthreads have no outstanding vmem to drain.
// ROUND 3: 8-wave blocks (two independent 4-wave chain-groups) for 2 waves/
// SIMD co-residency -- the two groups' per-step stall windows (ds_read, MFMA
// dep chain, tanh, barrier drain) interleave on each SIMD.
// ROUND-1 LESSON: __launch_bounds__(512, 2) capped VGPR at ~100 and spilled
// the GT=16 slab to scratch (112us). Declare ONLY the block size: 512 thr =
// 8 waves forces a 256-VGPR cap (enough for the ~168 natural pressure, no
// spills) while still guaranteeing 2 waves/SIMD.

#define TLEN 128
#define NSEQ 2048
#define PSH (NSEQ*64)   // f16 elems per t-slice
#define GT 16           // steps per group

typedef __bf16   bf16x8 __attribute__((ext_vector_type(8)));
typedef _Float16 f16x4  __attribute__((ext_vector_type(4)));
typedef float    f32x4  __attribute__((ext_vector_type(4)));
typedef unsigned short u16x4 __attribute__((ext_vector_type(4)));

static __device__ __forceinline__ unsigned int fbits(float f){
    union { float f; unsigned int u; } v; v.f = f; return v.u;
}
static __device__ __forceinline__ float ubits(unsigned int u){
    union { unsigned int u; float f; } v; v.u = u; return v.f;
}
static __device__ __forceinline__ float bf2f(unsigned short s){ return ubits(((unsigned int)s) << 16); }
static __device__ __forceinline__ unsigned short f2bf(float f){
    unsigned int u = fbits(f);
    return (unsigned short)((u + 0x7FFFu + ((u >> 16) & 1u)) >> 16);
}
static __device__ __forceinline__ __bf16 us2b(unsigned short s){
    union { unsigned short u; __bf16 b; } v; v.u = s; return v.b;
}
struct bfpair { __bf16 hi, lo; };
static __device__ __forceinline__ bfpair splitf(float f){   // RNE split (weights, once)
    unsigned short h = f2bf(f);
    bfpair r; r.hi = us2b(h); r.lo = us2b(f2bf(f - bf2f(h))); return r;
}
static __device__ __forceinline__ float fast_tanh(float x){
    float e = __builtin_amdgcn_exp2f(x * 2.8853900817779268f);
    return 1.0f - 2.0f * __builtin_amdgcn_rcpf(e + 1.0f);
}

// ---------------------------------------------------------------------------
// k_proj0: pre_x[w][b*128+h][j] = f16( sum_c x[b][c][h][w]*Wihx[j][c] + bias )
// bf16 hi/lo 3-term MFMA. Block 256thr/4 waves; wave: 32 rows x 64 j.
__global__ __launch_bounds__(256) void k_proj0(const float* __restrict__ A,
                                               const float* __restrict__ Wih,
                                               const float* __restrict__ b1,
                                               const float* __restrict__ b2,
                                               _Float16* __restrict__ pre){
    int lane = threadIdx.x & 63;
    int wv   = threadIdx.x >> 6;
    int q    = lane >> 4, l15 = lane & 15;

    bf16x8 Whi[4][2], Wlo[4][2];
#pragma unroll
    for (int n = 0; n < 4; n++)
#pragma unroll
        for (int kc = 0; kc < 2; kc++){
            const float* p = Wih + (n * 16 + l15) * 64 + kc * 32 + q * 8;
#pragma unroll
            for (int i = 0; i < 8; i++){
                bfpair s = splitf(p[i]);
                Whi[n][kc][i] = s.hi; Wlo[n][kc][i] = s.lo;
            }
        }
    float bias[4];
#pragma unroll
    for (int n = 0; n < 4; n++){
        int j = n * 16 + l15;
        bias[n] = b1[j] + b2[j];
    }

    int row0 = blockIdx.x * 128 + wv * 32;

    float av[2][2][8];
#pragma unroll
    for (int mi = 0; mi < 2; mi++){
        int r = row0 + mi * 16 + l15;
        int b = r >> 14, hw = r & 16383;
        const float* xb = A + (size_t)b * 1048576 + hw;
#pragma unroll
        for (int kc = 0; kc < 2; kc++)
#pragma unroll
            for (int i = 0; i < 8; i++)
                av[mi][kc][i] = xb[(size_t)(kc * 32 + q * 8 + i) * 16384];
    }

#pragma unroll
    for (int mi = 0; mi < 2; mi++){
        int rb = row0 + mi * 16;
        bf16x8 Ahi[2], Alo[2];
#pragma unroll
        for (int kc = 0; kc < 2; kc++)
#pragma unroll
            for (int i = 0; i < 8; i++){
                bfpair s = splitf(av[mi][kc][i]);
                Ahi[kc][i] = s.hi; Alo[kc][i] = s.lo;
            }
        f32x4 acc[4];
#pragma unroll
        for (int n = 0; n < 4; n++) acc[n] = (f32x4){bias[n], bias[n], bias[n], bias[n]};
#pragma unroll
        for (int n = 0; n < 4; n++)
#pragma unroll
            for (int kc = 0; kc < 2; kc++){
                acc[n] = __builtin_amdgcn_mfma_f32_16x16x32_bf16(Ahi[kc], Whi[n][kc], acc[n], 0, 0, 0);
                acc[n] = __builtin_amdgcn_mfma_f32_16x16x32_bf16(Alo[kc], Whi[n][kc], acc[n], 0, 0, 0);
                acc[n] = __builtin_amdgcn_mfma_f32_16x16x32_bf16(Ahi[kc], Wlo[n][kc], acc[n], 0, 0, 0);
            }
        // rows rb..rb+15 share (b,h); w = (rb&127) + q*4 + rr. seq_x = b*128+h.
        int bT = rb >> 14, hT = (rb >> 7) & 127, wBase = rb & 127;
        size_t seqOff = (size_t)bT * 128 + hT;
#pragma unroll
        for (int n = 0; n < 4; n++)
#pragma unroll
            for (int rr = 0; rr < 4; rr++){
                int w = wBase + q * 4 + rr;
                pre[((size_t)w * NSEQ + seqOff) * 64 + n * 16 + l15] = (_Float16)acc[n][rr];
            }
    }
}

// ---------------------------------------------------------------------------
// k_scan<PASS>: h_t = tanh(pre_t + Whh h_{t-1}), 64 blocks x 8 waves.
// TWO independent seq-groups per block (grp = tid>>8): each group is 4 waves,
// wave wv owns j-tile [wv*16,+16). Whh hi/lo pinned in VGPRs (A-frags).
// h exchanged via swizzled LDS (parity dbuf, per-group region) + one
// __syncthreads per step (couples both groups; their stalls overlap 2/SIMD).
// pre slab (16 steps) loaded into registers at group top; outputs staged in
// registers, burst-stored at group end -> barriers stay vmcnt-clean.
// PASS 0: fused Y-proj on B-frags (h_{t-1}) -> pre_y[t-1] f16 (incl bias_y).
// PASS 1: final out[b][j][t][w] fp32.
template<int PASS>
__global__ __launch_bounds__(512) void k_scan(const _Float16* __restrict__ pre,
                                              const float* __restrict__ Whh,
                                              const float* __restrict__ Wy,
                                              const float* __restrict__ by1,
                                              const float* __restrict__ by2,
                                              _Float16* __restrict__ prey,
                                              float* __restrict__ outf){
    __shared__ alignas(16) unsigned short hbuf[2][2][2][16][64];  // [grp][par][hi/lo]
    int lane = threadIdx.x & 63;
    int wv   = (threadIdx.x >> 6) & 3;
    int grp  = threadIdx.x >> 8;
    int q = lane >> 4, l15 = lane & 15;
    int n0 = blockIdx.x * 32 + grp * 16;
    int j0 = wv * 16 + q * 4;

    bf16x8 Ahi[2], Alo[2];
#pragma unroll
    for (int kc = 0; kc < 2; kc++){
        const float* p = Whh + (wv * 16 + l15) * 64 + kc * 32 + q * 8;
#pragma unroll
        for (int i = 0; i < 8; i++){
            bfpair s = splitf(p[i]);
            Ahi[kc][i] = s.hi; Alo[kc][i] = s.lo;
        }
    }
    bf16x8 Yhi[2], Ylo[2];
    f32x4  biasy = (f32x4){0.f, 0.f, 0.f, 0.f};
    if constexpr (PASS == 0){
#pragma unroll
        for (int kc = 0; kc < 2; kc++){
            const float* p = Wy + (wv * 16 + l15) * 64 + kc * 32 + q * 8;
#pragma unroll
            for (int i = 0; i < 8; i++){
                bfpair s = splitf(p[i]);
                Yhi[kc][i] = s.hi; Ylo[kc][i] = s.lo;
            }
        }
#pragma unroll
        for (int r = 0; r < 4; r++) biasy[r] = by1[j0 + r] + by2[j0 + r];
    }

    bf16x8 Bhi[2], Blo[2];
#pragma unroll
    for (int kc = 0; kc < 2; kc++)
#pragma unroll
        for (int i = 0; i < 8; i++){ Bhi[kc][i] = us2b(0); Blo[kc][i] = us2b(0); }

    int bb = n0 >> 7, low7 = n0 & 127;   // PASS0: h0 = low7; PASS1: w0 = low7

    const _Float16* pb = pre + (size_t)(n0 + l15) * 64 + j0;
    size_t spy = (size_t)(low7 + l15) * NSEQ + (size_t)bb * 128;  // PASS0 prey seq base

    int e   = l15 & 7;
    int wj  = (((j0 >> 3) ^ e) << 3) | (j0 & 7);
    int rj0 = ((q)     ^ e) << 3;
    int rj1 = ((4 + q) ^ e) << 3;

    f16x4 ps[GT];
    u16x4 prey_st[GT];
    f32x4 outst[GT];

    for (int g = 0; g < TLEN / GT; g++){
        int G = g * GT;
#pragma unroll
        for (int u = 0; u < GT; u++)
            ps[u] = *(const f16x4*)(pb + (size_t)(G + u) * PSH);

#pragma unroll
        for (int u = 0; u < GT; u++){
            int t = G + u;
            // ---- recurrence MFMAs first (critical path)
            f32x4 a0 = (f32x4){(float)ps[u][0], (float)ps[u][1], (float)ps[u][2], (float)ps[u][3]};
            f32x4 a1 = (f32x4){0.f, 0.f, 0.f, 0.f};
            f32x4 a2 = (f32x4){0.f, 0.f, 0.f, 0.f};
            a0 = __builtin_amdgcn_mfma_f32_16x16x32_bf16(Ahi[0], Bhi[0], a0, 0, 0, 0);
            a1 = __builtin_amdgcn_mfma_f32_16x16x32_bf16(Ahi[0], Blo[0], a1, 0, 0, 0);
            a2 = __builtin_amdgcn_mfma_f32_16x16x32_bf16(Alo[0], Bhi[0], a2, 0, 0, 0);
            a0 = __builtin_amdgcn_mfma_f32_16x16x32_bf16(Ahi[1], Bhi[1], a0, 0, 0, 0);
            a1 = __builtin_amdgcn_mfma_f32_16x16x32_bf16(Ahi[1], Blo[1], a1, 0, 0, 0);
            a2 = __builtin_amdgcn_mfma_f32_16x16x32_bf16(Alo[1], Bhi[1], a2, 0, 0, 0);
            // ---- fused Y-proj on current B (= h_{t-1}) -> pre_y[t-1]; fills
            //      the recurrence-MFMA latency window (independent of a-chain)
            if constexpr (PASS == 0){
                f32x4 y0 = biasy;
                f32x4 y1 = (f32x4){0.f, 0.f, 0.f, 0.f};
                y0 = __builtin_amdgcn_mfma_f32_16x16x32_bf16(Yhi[0], Bhi[0], y0, 0, 0, 0);
                y0 = __builtin_amdgcn_mfma_f32_16x16x32_bf16(Yhi[1], Bhi[1], y0, 0, 0, 0);
                y1 = __builtin_amdgcn_mfma_f32_16x16x32_bf16(Ylo[0], Bhi[0], y1, 0, 0, 0);
                y1 = __builtin_amdgcn_mfma_f32_16x16x32_bf16(Ylo[1], Bhi[1], y1, 0, 0, 0);
                y1 = __builtin_amdgcn_mfma_f32_16x16x32_bf16(Yhi[0], Blo[0], y1, 0, 0, 0);
                y1 = __builtin_amdgcn_mfma_f32_16x16x32_bf16(Yhi[1], Blo[1], y1, 0, 0, 0);
                f32x4 ys = y0 + y1;
#pragma unroll
                for (int r = 0; r < 4; r++){
                    union { _Float16 h; unsigned short s; } c;
                    c.h = (_Float16)ys[r];
                    prey_st[u][r] = c.s;
                }
            }
            f32x4 acc = (a0 + a1) + a2;

            u16x4 hi4, lo4;
#pragma unroll
            for (int r = 0; r < 4; r++){
                float tv = fast_tanh(acc[r]);
                if constexpr (PASS == 1) outst[u][r] = tv;
                unsigned int ub = fbits(tv);
                hi4[r] = (unsigned short)(ub >> 16);          // trunc-bf16 hi
                float lof = tv - ubits(ub & 0xFFFF0000u);     // exact remainder
                lo4[r] = (unsigned short)(fbits(lof) >> 16);  // trunc-bf16 lo
            }
            int par = t & 1;
            *(u16x4*)&hbuf[grp][par][0][l15][wj] = hi4;
            *(u16x4*)&hbuf[grp][par][1][l15][wj] = lo4;
            __syncthreads();
            Bhi[0] = *(const bf16x8*)&hbuf[grp][par][0][l15][rj0];
            Blo[0] = *(const bf16x8*)&hbuf[grp][par][1][l15][rj0];
            Bhi[1] = *(const bf16x8*)&hbuf[grp][par][0][l15][rj1];
            Blo[1] = *(const bf16x8*)&hbuf[grp][par][1][l15][rj1];
        }
        // ---- burst stores (drained once at next group's first barrier)
        if constexpr (PASS == 0){
#pragma unroll
            for (int u = 0; u < GT; u++){
                int tp = G - 1 + u;
                if (tp >= 0)
                    *(u16x4*)(prey + (spy + tp) * 64 + j0) = prey_st[u];
            }
        } else {
#pragma unroll
            for (int u = 0; u < GT; u++)
#pragma unroll
                for (int r = 0; r < 4; r++)
                    outf[((size_t)(bb * 64 + j0 + r) * TLEN + (G + u)) * 128 + low7 + l15] = outst[u][r];
        }
    }
    // tail: pre_y[127] from final B (= h_127)
    if constexpr (PASS == 0){
        f32x4 y0 = biasy;
        f32x4 y1 = (f32x4){0.f, 0.f, 0.f, 0.f};
        y0 = __builtin_amdgcn_mfma_f32_16x16x32_bf16(Yhi[0], Bhi[0], y0, 0, 0, 0);
        y0 = __builtin_amdgcn_mfma_f32_16x16x32_bf16(Yhi[1], Bhi[1], y0, 0, 0, 0);
        y1 = __builtin_amdgcn_mfma_f32_16x16x32_bf16(Ylo[0], Bhi[0], y1, 0, 0, 0);
        y1 = __builtin_amdgcn_mfma_f32_16x16x32_bf16(Ylo[1], Bhi[1], y1, 0, 0, 0);
        y1 = __builtin_amdgcn_mfma_f32_16x16x32_bf16(Yhi[0], Blo[0], y1, 0, 0, 0);
        y1 = __builtin_amdgcn_mfma_f32_16x16x32_bf16(Yhi[1], Blo[1], y1, 0, 0, 0);
        f32x4 ys = y0 + y1;
        u16x4 pv;
#pragma unroll
        for (int r = 0; r < 4; r++){
            union { _Float16 h; unsigned short s; } c;
            c.h = (_Float16)ys[r];
            pv[r] = c.s;
        }
        *(u16x4*)(prey + (spy + (TLEN - 1)) * 64 + j0) = pv;
    }
}

// ---------------------------------------------------------------------------
extern "C" void kernel_launch(void* const* d_in, const int* in_sizes, int n_in,
                              void* d_out, int out_size, void* d_ws, size_t ws_size,
                              hipStream_t stream){
    (void)in_sizes; (void)n_in; (void)out_size; (void)ws_size;
    const float* x    = (const float*)d_in[0];
    const float* Wihx = (const float*)d_in[1];
    const float* Whhx = (const float*)d_in[2];
    const float* bihx = (const float*)d_in[3];
    const float* bhhx = (const float*)d_in[4];
    const float* Wihy = (const float*)d_in[5];
    const float* Whhy = (const float*)d_in[6];
    const float* bihy = (const float*)d_in[7];
    const float* bhhy = (const float*)d_in[8];
    _Float16* prex = (_Float16*)d_ws;                          // 33.5MB
    _Float16* prey = prex + (size_t)NSEQ * TLEN * 64;          // 33.5MB
    float* of = (float*)d_out;

    k_proj0 <<<2048, 256, 0, stream>>>(x, Wihx, bihx, bhhx, prex);
    k_scan<0><<<64, 512, 0, stream>>>(prex, Whhx, Wihy, bihy, bhhy, prey, nullptr);
    k_scan<1><<<64, 512, 0, stream>>>(prey, Whhy, nullptr, nullptr, nullptr, nullptr, of);
}

// Round 4
// 335.887 us; speedup vs baseline: 1.0536x; 1.0054x over previous
//
#include <hip/hip_runtime.h>
#include <stdint.h>

// B=16, C=64, H=128, W=128, HX=HY=64. All I/O fp32.
// Pipeline (3 kernels):
//   k_proj0 : pre_x[t=w][seq=(b,h)][j] (f16, incl bias) = Wihx·x + b
//   k_scan<0>: X recurrence; FUSED Y-projection -> pre_y[t=h][seq=(b,w)][j] (f16, incl bias)
//   k_scan<1>: Y recurrence -> out[b][j][h][w] fp32
// d_ws: pre_x (33.5MB) + pre_y (33.5MB) = 67MB.
// ROUND 4: WAVE-SPLIT DUAL CHAIN. 256-thr block (the only shape the
// allocator treats well: rounds 1/3 proved 512-thr blocks get sandbagged to
// 100 VGPR; round 2 proved intra-wave dual-chain gets serialized). Waves
// {0,1} own chain A, waves {2,3} own chain B; each wave computes 32 j-cols
// (2 MFMA n-tiles). Two chain-steps retire per barrier-tick on different
// SIMDs -- hardware parallelism the compiler cannot serialize. Weights are
// chain-invariant (no extra regs); GT=8 keeps pressure ~200.

#define TLEN 128
#define NSEQ 2048
#define PSH (NSEQ*64)   // f16 elems per t-slice
#define GT 8            // steps per group

typedef __bf16   bf16x8 __attribute__((ext_vector_type(8)));
typedef _Float16 f16x4  __attribute__((ext_vector_type(4)));
typedef float    f32x4  __attribute__((ext_vector_type(4)));
typedef unsigned short u16x4 __attribute__((ext_vector_type(4)));

static __device__ __forceinline__ unsigned int fbits(float f){
    union { float f; unsigned int u; } v; v.f = f; return v.u;
}
static __device__ __forceinline__ float ubits(unsigned int u){
    union { unsigned int u; float f; } v; v.u = u; return v.f;
}
static __device__ __forceinline__ float bf2f(unsigned short s){ return ubits(((unsigned int)s) << 16); }
static __device__ __forceinline__ unsigned short f2bf(float f){
    unsigned int u = fbits(f);
    return (unsigned short)((u + 0x7FFFu + ((u >> 16) & 1u)) >> 16);
}
static __device__ __forceinline__ __bf16 us2b(unsigned short s){
    union { unsigned short u; __bf16 b; } v; v.u = s; return v.b;
}
struct bfpair { __bf16 hi, lo; };
static __device__ __forceinline__ bfpair splitf(float f){   // RNE split (weights, once)
    unsigned short h = f2bf(f);
    bfpair r; r.hi = us2b(h); r.lo = us2b(f2bf(f - bf2f(h))); return r;
}
static __device__ __forceinline__ float fast_tanh(float x){
    float e = __builtin_amdgcn_exp2f(x * 2.8853900817779268f);
    return 1.0f - 2.0f * __builtin_amdgcn_rcpf(e + 1.0f);
}

// ---------------------------------------------------------------------------
// k_proj0: pre_x[w][b*128+h][j] = f16( sum_c x[b][c][h][w]*Wihx[j][c] + bias )
// bf16 hi/lo 3-term MFMA. Block 256thr/4 waves; wave: 32 rows x 64 j.
__global__ __launch_bounds__(256) void k_proj0(const float* __restrict__ A,
                                               const float* __restrict__ Wih,
                                               const float* __restrict__ b1,
                                               const float* __restrict__ b2,
                                               _Float16* __restrict__ pre){
    int lane = threadIdx.x & 63;
    int wv   = threadIdx.x >> 6;
    int q    = lane >> 4, l15 = lane & 15;

    bf16x8 Whi[4][2], Wlo[4][2];
#pragma unroll
    for (int n = 0; n < 4; n++)
#pragma unroll
        for (int kc = 0; kc < 2; kc++){
            const float* p = Wih + (n * 16 + l15) * 64 + kc * 32 + q * 8;
#pragma unroll
            for (int i = 0; i < 8; i++){
                bfpair s = splitf(p[i]);
                Whi[n][kc][i] = s.hi; Wlo[n][kc][i] = s.lo;
            }
        }
    float bias[4];
#pragma unroll
    for (int n = 0; n < 4; n++){
        int j = n * 16 + l15;
        bias[n] = b1[j] + b2[j];
    }

    int row0 = blockIdx.x * 128 + wv * 32;

    float av[2][2][8];
#pragma unroll
    for (int mi = 0; mi < 2; mi++){
        int r = row0 + mi * 16 + l15;
        int b = r >> 14, hw = r & 16383;
        const float* xb = A + (size_t)b * 1048576 + hw;
#pragma unroll
        for (int kc = 0; kc < 2; kc++)
#pragma unroll
            for (int i = 0; i < 8; i++)
                av[mi][kc][i] = xb[(size_t)(kc * 32 + q * 8 + i) * 16384];
    }

#pragma unroll
    for (int mi = 0; mi < 2; mi++){
        int rb = row0 + mi * 16;
        bf16x8 Ahi[2], Alo[2];
#pragma unroll
        for (int kc = 0; kc < 2; kc++)
#pragma unroll
            for (int i = 0; i < 8; i++){
                bfpair s = splitf(av[mi][kc][i]);
                Ahi[kc][i] = s.hi; Alo[kc][i] = s.lo;
            }
        f32x4 acc[4];
#pragma unroll
        for (int n = 0; n < 4; n++) acc[n] = (f32x4){bias[n], bias[n], bias[n], bias[n]};
#pragma unroll
        for (int n = 0; n < 4; n++)
#pragma unroll
            for (int kc = 0; kc < 2; kc++){
                acc[n] = __builtin_amdgcn_mfma_f32_16x16x32_bf16(Ahi[kc], Whi[n][kc], acc[n], 0, 0, 0);
                acc[n] = __builtin_amdgcn_mfma_f32_16x16x32_bf16(Alo[kc], Whi[n][kc], acc[n], 0, 0, 0);
                acc[n] = __builtin_amdgcn_mfma_f32_16x16x32_bf16(Ahi[kc], Wlo[n][kc], acc[n], 0, 0, 0);
            }
        // rows rb..rb+15 share (b,h); w = (rb&127) + q*4 + rr. seq_x = b*128+h.
        int bT = rb >> 14, hT = (rb >> 7) & 127, wBase = rb & 127;
        size_t seqOff = (size_t)bT * 128 + hT;
#pragma unroll
        for (int n = 0; n < 4; n++)
#pragma unroll
            for (int rr = 0; rr < 4; rr++){
                int w = wBase + q * 4 + rr;
                pre[((size_t)w * NSEQ + seqOff) * 64 + n * 16 + l15] = (_Float16)acc[n][rr];
            }
    }
}

// ---------------------------------------------------------------------------
// k_scan<PASS>: h_t = tanh(pre_t + Whh h_{t-1}), 64 blocks x 4 waves.
// Waves {0,1} = chain A (seqs n0..n0+15), waves {2,3} = chain B (+16..+31).
// Wave (cg,wh): chain cg, j-cols [wh*32, wh*32+32) = 2 MFMA n-tiles.
// Whh/Wy hi/lo pinned in VGPRs (chain-invariant). h exchanged via swizzled
// LDS (parity dbuf, per-chain region) + one __syncthreads per step serving
// BOTH chains (2 chain-steps/barrier on disjoint SIMDs). pre slab (GT steps)
// loaded into regs at group top; outputs staged in regs, burst-stored at
// group end -> barriers stay vmcnt-clean except once per group.
// PASS 0: fused Y-proj on B-frags (h_{t-1}) -> pre_y[t-1] f16 (incl bias_y).
// PASS 1: final out[b][j][t][w] fp32.
template<int PASS>
__global__ __launch_bounds__(256) void k_scan(const _Float16* __restrict__ pre,
                                              const float* __restrict__ Whh,
                                              const float* __restrict__ Wy,
                                              const float* __restrict__ by1,
                                              const float* __restrict__ by2,
                                              _Float16* __restrict__ prey,
                                              float* __restrict__ outf){
    __shared__ alignas(16) unsigned short hbuf[2][2][2][16][64];  // [chain][par][hi/lo]
    int lane = threadIdx.x & 63;
    int wv   = threadIdx.x >> 6;
    int cg   = wv >> 1;          // chain group
    int wh   = wv & 1;           // j-half: cols [wh*32, +32)
    int q = lane >> 4, l15 = lane & 15;
    int n0 = blockIdx.x * 32 + cg * 16;
    int j00 = wh * 32 + q * 4;   // tile n'=0 base col (tile 1 at +16)

    // weights: 2 n-tiles (global n = wh*2+n')
    bf16x8 Ahi[2][2], Alo[2][2];
#pragma unroll
    for (int np = 0; np < 2; np++)
#pragma unroll
        for (int kc = 0; kc < 2; kc++){
            const float* p = Whh + ((wh * 2 + np) * 16 + l15) * 64 + kc * 32 + q * 8;
#pragma unroll
            for (int i = 0; i < 8; i++){
                bfpair s = splitf(p[i]);
                Ahi[np][kc][i] = s.hi; Alo[np][kc][i] = s.lo;
            }
        }
    bf16x8 Yhi[2][2], Ylo[2][2];
    f32x4  biasy[2] = {(f32x4){0.f,0.f,0.f,0.f}, (f32x4){0.f,0.f,0.f,0.f}};
    if constexpr (PASS == 0){
#pragma unroll
        for (int np = 0; np < 2; np++){
#pragma unroll
            for (int kc = 0; kc < 2; kc++){
                const float* p = Wy + ((wh * 2 + np) * 16 + l15) * 64 + kc * 32 + q * 8;
#pragma unroll
                for (int i = 0; i < 8; i++){
                    bfpair s = splitf(p[i]);
                    Yhi[np][kc][i] = s.hi; Ylo[np][kc][i] = s.lo;
                }
            }
#pragma unroll
            for (int r = 0; r < 4; r++)
                biasy[np][r] = by1[j00 + np * 16 + r] + by2[j00 + np * 16 + r];
        }
    }

    bf16x8 Bhi[2], Blo[2];       // h frags (kc), shared by both n-tiles
#pragma unroll
    for (int kc = 0; kc < 2; kc++)
#pragma unroll
        for (int i = 0; i < 8; i++){ Bhi[kc][i] = us2b(0); Blo[kc][i] = us2b(0); }

    int bb = n0 >> 7, low7 = n0 & 127;   // PASS0: h0 = low7; PASS1: w0 = low7

    const _Float16* pb = pre + (size_t)(n0 + l15) * 64 + j00;
    size_t spy = (size_t)(low7 + l15) * NSEQ + (size_t)bb * 128;  // PASS0 prey seq base

    int e   = l15 & 7;
    // write cols per tile: j0n = (wh*2+np)*16 + q*4
    int wj0 = ((((wh * 2 + 0) * 2 + (q >> 1)) ^ e) << 3) | ((q & 1) * 4);
    int wj1 = ((((wh * 2 + 1) * 2 + (q >> 1)) ^ e) << 3) | ((q & 1) * 4);
    int rj0 = ((q)     ^ e) << 3;
    int rj1 = ((4 + q) ^ e) << 3;

    f16x4 ps[2][GT];
    u16x4 prey_st[2][GT];
    f32x4 outst[2][GT];

    for (int g = 0; g < TLEN / GT; g++){
        int G = g * GT;
#pragma unroll
        for (int u = 0; u < GT; u++){
            ps[0][u] = *(const f16x4*)(pb + (size_t)(G + u) * PSH);
            ps[1][u] = *(const f16x4*)(pb + (size_t)(G + u) * PSH + 16);
        }

#pragma unroll
        for (int u = 0; u < GT; u++){
            int t = G + u;
            int par = t & 1;
#pragma unroll
            for (int np = 0; np < 2; np++){
                // recurrence MFMAs (critical path)
                f32x4 a0 = (f32x4){(float)ps[np][u][0], (float)ps[np][u][1],
                                   (float)ps[np][u][2], (float)ps[np][u][3]};
                f32x4 a1 = (f32x4){0.f, 0.f, 0.f, 0.f};
                f32x4 a2 = (f32x4){0.f, 0.f, 0.f, 0.f};
                a0 = __builtin_amdgcn_mfma_f32_16x16x32_bf16(Ahi[np][0], Bhi[0], a0, 0, 0, 0);
                a1 = __builtin_amdgcn_mfma_f32_16x16x32_bf16(Ahi[np][0], Blo[0], a1, 0, 0, 0);
                a2 = __builtin_amdgcn_mfma_f32_16x16x32_bf16(Alo[np][0], Bhi[0], a2, 0, 0, 0);
                a0 = __builtin_amdgcn_mfma_f32_16x16x32_bf16(Ahi[np][1], Bhi[1], a0, 0, 0, 0);
                a1 = __builtin_amdgcn_mfma_f32_16x16x32_bf16(Ahi[np][1], Blo[1], a1, 0, 0, 0);
                a2 = __builtin_amdgcn_mfma_f32_16x16x32_bf16(Alo[np][1], Bhi[1], a2, 0, 0, 0);
                // fused Y-proj on current B (= h_{t-1}) -> pre_y[t-1]
                if constexpr (PASS == 0){
                    f32x4 y0 = biasy[np];
                    f32x4 y1 = (f32x4){0.f, 0.f, 0.f, 0.f};
                    y0 = __builtin_amdgcn_mfma_f32_16x16x32_bf16(Yhi[np][0], Bhi[0], y0, 0, 0, 0);
                    y0 = __builtin_amdgcn_mfma_f32_16x16x32_bf16(Yhi[np][1], Bhi[1], y0, 0, 0, 0);
                    y1 = __builtin_amdgcn_mfma_f32_16x16x32_bf16(Ylo[np][0], Bhi[0], y1, 0, 0, 0);
                    y1 = __builtin_amdgcn_mfma_f32_16x16x32_bf16(Ylo[np][1], Bhi[1], y1, 0, 0, 0);
                    y1 = __builtin_amdgcn_mfma_f32_16x16x32_bf16(Yhi[np][0], Blo[0], y1, 0, 0, 0);
                    y1 = __builtin_amdgcn_mfma_f32_16x16x32_bf16(Yhi[np][1], Blo[1], y1, 0, 0, 0);
                    f32x4 ys = y0 + y1;
#pragma unroll
                    for (int r = 0; r < 4; r++){
                        union { _Float16 h; unsigned short s; } cv;
                        cv.h = (_Float16)ys[r];
                        prey_st[np][u][r] = cv.s;
                    }
                }
                f32x4 acc = (a0 + a1) + a2;

                u16x4 hi4, lo4;
#pragma unroll
                for (int r = 0; r < 4; r++){
                    float tv = fast_tanh(acc[r]);
                    if constexpr (PASS == 1) outst[np][u][r] = tv;
                    unsigned int ub = fbits(tv);
                    hi4[r] = (unsigned short)(ub >> 16);          // trunc-bf16 hi
                    float lof = tv - ubits(ub & 0xFFFF0000u);     // exact remainder
                    lo4[r] = (unsigned short)(fbits(lof) >> 16);  // trunc-bf16 lo
                }
                int wjn = np ? wj1 : wj0;
                *(u16x4*)&hbuf[cg][par][0][l15][wjn] = hi4;
                *(u16x4*)&hbuf[cg][par][1][l15][wjn] = lo4;
            }
            __syncthreads();
            Bhi[0] = *(const bf16x8*)&hbuf[cg][par][0][l15][rj0];
            Blo[0] = *(const bf16x8*)&hbuf[cg][par][1][l15][rj0];
            Bhi[1] = *(const bf16x8*)&hbuf[cg][par][0][l15][rj1];
            Blo[1] = *(const bf16x8*)&hbuf[cg][par][1][l15][rj1];
        }
        // ---- burst stores (drained once at next group's first barrier)
        if constexpr (PASS == 0){
#pragma unroll
            for (int np = 0; np < 2; np++)
#pragma unroll
                for (int u = 0; u < GT; u++){
                    int tp = G - 1 + u;
                    if (tp >= 0)
                        *(u16x4*)(prey + (spy + tp) * 64 + j00 + np * 16) = prey_st[np][u];
                }
        } else {
#pragma unroll
            for (int np = 0; np < 2; np++)
#pragma unroll
                for (int u = 0; u < GT; u++)
#pragma unroll
                    for (int r = 0; r < 4; r++)
                        outf[((size_t)(bb * 64 + j00 + np * 16 + r) * TLEN + (G + u)) * 128
                             + low7 + l15] = outst[np][u][r];
        }
    }
    // tail: pre_y[127] from final B (= h_127)
    if constexpr (PASS == 0){
#pragma unroll
        for (int np = 0; np < 2; np++){
            f32x4 y0 = biasy[np];
            f32x4 y1 = (f32x4){0.f, 0.f, 0.f, 0.f};
            y0 = __builtin_amdgcn_mfma_f32_16x16x32_bf16(Yhi[np][0], Bhi[0], y0, 0, 0, 0);
            y0 = __builtin_amdgcn_mfma_f32_16x16x32_bf16(Yhi[np][1], Bhi[1], y0, 0, 0, 0);
            y1 = __builtin_amdgcn_mfma_f32_16x16x32_bf16(Ylo[np][0], Bhi[0], y1, 0, 0, 0);
            y1 = __builtin_amdgcn_mfma_f32_16x16x32_bf16(Ylo[np][1], Bhi[1], y1, 0, 0, 0);
            y1 = __builtin_amdgcn_mfma_f32_16x16x32_bf16(Yhi[np][0], Blo[0], y1, 0, 0, 0);
            y1 = __builtin_amdgcn_mfma_f32_16x16x32_bf16(Yhi[np][1], Blo[1], y1, 0, 0, 0);
            f32x4 ys = y0 + y1;
            u16x4 pv;
#pragma unroll
            for (int r = 0; r < 4; r++){
                union { _Float16 h; unsigned short s; } cv;
                cv.h = (_Float16)ys[r];
                pv[r] = cv.s;
            }
            *(u16x4*)(prey + (spy + (TLEN - 1)) * 64 + j00 + np * 16) = pv;
        }
    }
}

// ---------------------------------------------------------------------------
extern "C" void kernel_launch(void* const* d_in, const int* in_sizes, int n_in,
                              void* d_out, int out_size, void* d_ws, size_t ws_size,
                              hipStream_t stream){
    (void)in_sizes; (void)n_in; (void)out_size; (void)ws_size;
    const float* x    = (const float*)d_in[0];
    const float* Wihx = (const float*)d_in[1];
    const float* Whhx = (const float*)d_in[2];
    const float* bihx = (const float*)d_in[3];
    const float* bhhx = (const float*)d_in[4];
    const float* Wihy = (const float*)d_in[5];
    const float* Whhy = (const float*)d_in[6];
    const float* bihy = (const float*)d_in[7];
    const float* bhhy = (const float*)d_in[8];
    _Float16* prex = (_Float16*)d_ws;                          // 33.5MB
    _Float16* prey = prex + (size_t)NSEQ * TLEN * 64;          // 33.5MB
    float* of = (float*)d_out;

    k_proj0 <<<2048, 256, 0, stream>>>(x, Wihx, bihx, bhhx, prex);
    k_scan<0><<<64, 256, 0, stream>>>(prex, Whhx, Wihy, bihy, bhhy, prey, nullptr);
    k_scan<1><<<64, 256, 0, stream>>>(prey, Whhy, nullptr, nullptr, nullptr, nullptr, of);
}

// Round 5
// 331.697 us; speedup vs baseline: 1.0669x; 1.0126x over previous
//
#include <hip/hip_runtime.h>
#include <stdint.h>

// B=16, C=64, H=128, W=128, HX=HY=64. All I/O fp32.
// Pipeline (3 kernels):
//   k_proj0 : pre_x[t=w][seq=(b,h)][j] (f16, incl bias) = Wihx·x + b
//   k_scan<0>: X recurrence; FUSED Y-projection -> pre_y[t=h][seq=(b,w)][j] (f16, incl bias)
//   k_scan<1>: Y recurrence -> out[b][j][h][w] fp32
// d_ws: pre_x (33.5MB) + pre_y (33.5MB) = 67MB.
// ROUND 5: 8-wave blocks (two independent 4-wave chain-groups) = 2 waves/SIMD
// co-residency, WITH amdgpu_waves_per_eu(2,2) to stop the allocator sandbag.
// Empirical laws so far: tick = ~200ns + ~26ns/MFMA issued per wave (rounds
// 0/2/4) -> extra work IN a wave is serial; a second chain must be a second
// WAVE on the same SIMD. Rounds 1/3 proved 512-thr blocks default to ~100
// VGPR (spills slab -> 112us); waves_per_eu(2,2) budgets 256 VGPR/wave so
// the ~168-reg natural pressure fits and the two co-resident waves overlap
// issue/latency in hardware.

#define TLEN 128
#define NSEQ 2048
#define PSH (NSEQ*64)   // f16 elems per t-slice
#define GT 16           // steps per group

typedef __bf16   bf16x8 __attribute__((ext_vector_type(8)));
typedef _Float16 f16x4  __attribute__((ext_vector_type(4)));
typedef float    f32x4  __attribute__((ext_vector_type(4)));
typedef unsigned short u16x4 __attribute__((ext_vector_type(4)));

static __device__ __forceinline__ unsigned int fbits(float f){
    union { float f; unsigned int u; } v; v.f = f; return v.u;
}
static __device__ __forceinline__ float ubits(unsigned int u){
    union { unsigned int u; float f; } v; v.u = u; return v.f;
}
static __device__ __forceinline__ float bf2f(unsigned short s){ return ubits(((unsigned int)s) << 16); }
static __device__ __forceinline__ unsigned short f2bf(float f){
    unsigned int u = fbits(f);
    return (unsigned short)((u + 0x7FFFu + ((u >> 16) & 1u)) >> 16);
}
static __device__ __forceinline__ __bf16 us2b(unsigned short s){
    union { unsigned short u; __bf16 b; } v; v.u = s; return v.b;
}
struct bfpair { __bf16 hi, lo; };
static __device__ __forceinline__ bfpair splitf(float f){   // RNE split (weights, once)
    unsigned short h = f2bf(f);
    bfpair r; r.hi = us2b(h); r.lo = us2b(f2bf(f - bf2f(h))); return r;
}
static __device__ __forceinline__ float fast_tanh(float x){
    float e = __builtin_amdgcn_exp2f(x * 2.8853900817779268f);
    return 1.0f - 2.0f * __builtin_amdgcn_rcpf(e + 1.0f);
}

// ---------------------------------------------------------------------------
// k_proj0: pre_x[w][b*128+h][j] = f16( sum_c x[b][c][h][w]*Wihx[j][c] + bias )
// bf16 hi/lo 3-term MFMA. Block 256thr/4 waves; wave: 32 rows x 64 j.
__global__ __launch_bounds__(256) void k_proj0(const float* __restrict__ A,
                                               const float* __restrict__ Wih,
                                               const float* __restrict__ b1,
                                               const float* __restrict__ b2,
                                               _Float16* __restrict__ pre){
    int lane = threadIdx.x & 63;
    int wv   = threadIdx.x >> 6;
    int q    = lane >> 4, l15 = lane & 15;

    bf16x8 Whi[4][2], Wlo[4][2];
#pragma unroll
    for (int n = 0; n < 4; n++)
#pragma unroll
        for (int kc = 0; kc < 2; kc++){
            const float* p = Wih + (n * 16 + l15) * 64 + kc * 32 + q * 8;
#pragma unroll
            for (int i = 0; i < 8; i++){
                bfpair s = splitf(p[i]);
                Whi[n][kc][i] = s.hi; Wlo[n][kc][i] = s.lo;
            }
        }
    float bias[4];
#pragma unroll
    for (int n = 0; n < 4; n++){
        int j = n * 16 + l15;
        bias[n] = b1[j] + b2[j];
    }

    int row0 = blockIdx.x * 128 + wv * 32;

    float av[2][2][8];
#pragma unroll
    for (int mi = 0; mi < 2; mi++){
        int r = row0 + mi * 16 + l15;
        int b = r >> 14, hw = r & 16383;
        const float* xb = A + (size_t)b * 1048576 + hw;
#pragma unroll
        for (int kc = 0; kc < 2; kc++)
#pragma unroll
            for (int i = 0; i < 8; i++)
                av[mi][kc][i] = xb[(size_t)(kc * 32 + q * 8 + i) * 16384];
    }

#pragma unroll
    for (int mi = 0; mi < 2; mi++){
        int rb = row0 + mi * 16;
        bf16x8 Ahi[2], Alo[2];
#pragma unroll
        for (int kc = 0; kc < 2; kc++)
#pragma unroll
            for (int i = 0; i < 8; i++){
                bfpair s = splitf(av[mi][kc][i]);
                Ahi[kc][i] = s.hi; Alo[kc][i] = s.lo;
            }
        f32x4 acc[4];
#pragma unroll
        for (int n = 0; n < 4; n++) acc[n] = (f32x4){bias[n], bias[n], bias[n], bias[n]};
#pragma unroll
        for (int n = 0; n < 4; n++)
#pragma unroll
            for (int kc = 0; kc < 2; kc++){
                acc[n] = __builtin_amdgcn_mfma_f32_16x16x32_bf16(Ahi[kc], Whi[n][kc], acc[n], 0, 0, 0);
                acc[n] = __builtin_amdgcn_mfma_f32_16x16x32_bf16(Alo[kc], Whi[n][kc], acc[n], 0, 0, 0);
                acc[n] = __builtin_amdgcn_mfma_f32_16x16x32_bf16(Ahi[kc], Wlo[n][kc], acc[n], 0, 0, 0);
            }
        // rows rb..rb+15 share (b,h); w = (rb&127) + q*4 + rr. seq_x = b*128+h.
        int bT = rb >> 14, hT = (rb >> 7) & 127, wBase = rb & 127;
        size_t seqOff = (size_t)bT * 128 + hT;
#pragma unroll
        for (int n = 0; n < 4; n++)
#pragma unroll
            for (int rr = 0; rr < 4; rr++){
                int w = wBase + q * 4 + rr;
                pre[((size_t)w * NSEQ + seqOff) * 64 + n * 16 + l15] = (_Float16)acc[n][rr];
            }
    }
}

// ---------------------------------------------------------------------------
// k_scan<PASS>: h_t = tanh(pre_t + Whh h_{t-1}), 64 blocks x 8 waves.
// TWO independent seq-groups per block (grp = tid>>8): each group is 4 waves,
// wave wv owns j-tile [wv*16,+16). Whh hi/lo pinned in VGPRs (A-frags).
// h exchanged via swizzled LDS (parity dbuf) + one __syncthreads per step
// (couples both groups; their stalls overlap at 2 waves/SIMD).
// pre slab (16 steps) loaded into registers at group top; outputs staged in
// registers, burst-stored at group end -> barriers stay vmcnt-clean.
// amdgpu_waves_per_eu(2,2): pins allocator to a 256-VGPR/wave budget (the
// ~168 natural pressure fits, no spill) and exactly 2 waves/EU residency.
// PASS 0: fused Y-proj on B-frags (h_{t-1}) -> pre_y[t-1] f16 (incl bias_y).
// PASS 1: final out[b][j][t][w] fp32.
template<int PASS>
__global__ __launch_bounds__(512)
__attribute__((amdgpu_waves_per_eu(2, 2)))
void k_scan(const _Float16* __restrict__ pre,
            const float* __restrict__ Whh,
            const float* __restrict__ Wy,
            const float* __restrict__ by1,
            const float* __restrict__ by2,
            _Float16* __restrict__ prey,
            float* __restrict__ outf){
    __shared__ alignas(16) unsigned short hbuf[2][2][2][16][64];  // [grp][par][hi/lo]
    int lane = threadIdx.x & 63;
    int wv   = (threadIdx.x >> 6) & 3;
    int grp  = threadIdx.x >> 8;
    int q = lane >> 4, l15 = lane & 15;
    int n0 = blockIdx.x * 32 + grp * 16;
    int j0 = wv * 16 + q * 4;

    bf16x8 Ahi[2], Alo[2];
#pragma unroll
    for (int kc = 0; kc < 2; kc++){
        const float* p = Whh + (wv * 16 + l15) * 64 + kc * 32 + q * 8;
#pragma unroll
        for (int i = 0; i < 8; i++){
            bfpair s = splitf(p[i]);
            Ahi[kc][i] = s.hi; Alo[kc][i] = s.lo;
        }
    }
    bf16x8 Yhi[2], Ylo[2];
    f32x4  biasy = (f32x4){0.f, 0.f, 0.f, 0.f};
    if constexpr (PASS == 0){
#pragma unroll
        for (int kc = 0; kc < 2; kc++){
            const float* p = Wy + (wv * 16 + l15) * 64 + kc * 32 + q * 8;
#pragma unroll
            for (int i = 0; i < 8; i++){
                bfpair s = splitf(p[i]);
                Yhi[kc][i] = s.hi; Ylo[kc][i] = s.lo;
            }
        }
#pragma unroll
        for (int r = 0; r < 4; r++) biasy[r] = by1[j0 + r] + by2[j0 + r];
    }

    bf16x8 Bhi[2], Blo[2];
#pragma unroll
    for (int kc = 0; kc < 2; kc++)
#pragma unroll
        for (int i = 0; i < 8; i++){ Bhi[kc][i] = us2b(0); Blo[kc][i] = us2b(0); }

    int bb = n0 >> 7, low7 = n0 & 127;   // PASS0: h0 = low7; PASS1: w0 = low7

    const _Float16* pb = pre + (size_t)(n0 + l15) * 64 + j0;
    size_t spy = (size_t)(low7 + l15) * NSEQ + (size_t)bb * 128;  // PASS0 prey seq base

    int e   = l15 & 7;
    int wj  = (((j0 >> 3) ^ e) << 3) | (j0 & 7);
    int rj0 = ((q)     ^ e) << 3;
    int rj1 = ((4 + q) ^ e) << 3;

    f16x4 ps[GT];
    u16x4 prey_st[GT];
    f32x4 outst[GT];

    for (int g = 0; g < TLEN / GT; g++){
        int G = g * GT;
#pragma unroll
        for (int u = 0; u < GT; u++)
            ps[u] = *(const f16x4*)(pb + (size_t)(G + u) * PSH);

#pragma unroll
        for (int u = 0; u < GT; u++){
            int t = G + u;
            // ---- recurrence MFMAs first (critical path)
            f32x4 a0 = (f32x4){(float)ps[u][0], (float)ps[u][1], (float)ps[u][2], (float)ps[u][3]};
            f32x4 a1 = (f32x4){0.f, 0.f, 0.f, 0.f};
            f32x4 a2 = (f32x4){0.f, 0.f, 0.f, 0.f};
            a0 = __builtin_amdgcn_mfma_f32_16x16x32_bf16(Ahi[0], Bhi[0], a0, 0, 0, 0);
            a1 = __builtin_amdgcn_mfma_f32_16x16x32_bf16(Ahi[0], Blo[0], a1, 0, 0, 0);
            a2 = __builtin_amdgcn_mfma_f32_16x16x32_bf16(Alo[0], Bhi[0], a2, 0, 0, 0);
            a0 = __builtin_amdgcn_mfma_f32_16x16x32_bf16(Ahi[1], Bhi[1], a0, 0, 0, 0);
            a1 = __builtin_amdgcn_mfma_f32_16x16x32_bf16(Ahi[1], Blo[1], a1, 0, 0, 0);
            a2 = __builtin_amdgcn_mfma_f32_16x16x32_bf16(Alo[1], Bhi[1], a2, 0, 0, 0);
            // ---- fused Y-proj on current B (= h_{t-1}) -> pre_y[t-1]; fills
            //      the recurrence-MFMA latency window (independent of a-chain)
            if constexpr (PASS == 0){
                f32x4 y0 = biasy;
                f32x4 y1 = (f32x4){0.f, 0.f, 0.f, 0.f};
                y0 = __builtin_amdgcn_mfma_f32_16x16x32_bf16(Yhi[0], Bhi[0], y0, 0, 0, 0);
                y0 = __builtin_amdgcn_mfma_f32_16x16x32_bf16(Yhi[1], Bhi[1], y0, 0, 0, 0);
                y1 = __builtin_amdgcn_mfma_f32_16x16x32_bf16(Ylo[0], Bhi[0], y1, 0, 0, 0);
                y1 = __builtin_amdgcn_mfma_f32_16x16x32_bf16(Ylo[1], Bhi[1], y1, 0, 0, 0);
                y1 = __builtin_amdgcn_mfma_f32_16x16x32_bf16(Yhi[0], Blo[0], y1, 0, 0, 0);
                y1 = __builtin_amdgcn_mfma_f32_16x16x32_bf16(Yhi[1], Blo[1], y1, 0, 0, 0);
                f32x4 ys = y0 + y1;
#pragma unroll
                for (int r = 0; r < 4; r++){
                    union { _Float16 h; unsigned short s; } c;
                    c.h = (_Float16)ys[r];
                    prey_st[u][r] = c.s;
                }
            }
            f32x4 acc = (a0 + a1) + a2;

            u16x4 hi4, lo4;
#pragma unroll
            for (int r = 0; r < 4; r++){
                float tv = fast_tanh(acc[r]);
                if constexpr (PASS == 1) outst[u][r] = tv;
                unsigned int ub = fbits(tv);
                hi4[r] = (unsigned short)(ub >> 16);          // trunc-bf16 hi
                float lof = tv - ubits(ub & 0xFFFF0000u);     // exact remainder
                lo4[r] = (unsigned short)(fbits(lof) >> 16);  // trunc-bf16 lo
            }
            int par = t & 1;
            *(u16x4*)&hbuf[grp][par][0][l15][wj] = hi4;
            *(u16x4*)&hbuf[grp][par][1][l15][wj] = lo4;
            __syncthreads();
            Bhi[0] = *(const bf16x8*)&hbuf[grp][par][0][l15][rj0];
            Blo[0] = *(const bf16x8*)&hbuf[grp][par][1][l15][rj0];
            Bhi[1] = *(const bf16x8*)&hbuf[grp][par][0][l15][rj1];
            Blo[1] = *(const bf16x8*)&hbuf[grp][par][1][l15][rj1];
        }
        // ---- burst stores (drained once at next group's first barrier)
        if constexpr (PASS == 0){
#pragma unroll
            for (int u = 0; u < GT; u++){
                int tp = G - 1 + u;
                if (tp >= 0)
                    *(u16x4*)(prey + (spy + tp) * 64 + j0) = prey_st[u];
            }
        } else {
#pragma unroll
            for (int u = 0; u < GT; u++)
#pragma unroll
                for (int r = 0; r < 4; r++)
                    outf[((size_t)(bb * 64 + j0 + r) * TLEN + (G + u)) * 128 + low7 + l15] = outst[u][r];
        }
    }
    // tail: pre_y[127] from final B (= h_127)
    if constexpr (PASS == 0){
        f32x4 y0 = biasy;
        f32x4 y1 = (f32x4){0.f, 0.f, 0.f, 0.f};
        y0 = __builtin_amdgcn_mfma_f32_16x16x32_bf16(Yhi[0], Bhi[0], y0, 0, 0, 0);
        y0 = __builtin_amdgcn_mfma_f32_16x16x32_bf16(Yhi[1], Bhi[1], y0, 0, 0, 0);
        y1 = __builtin_amdgcn_mfma_f32_16x16x32_bf16(Ylo[0], Bhi[0], y1, 0, 0, 0);
        y1 = __builtin_amdgcn_mfma_f32_16x16x32_bf16(Ylo[1], Bhi[1], y1, 0, 0, 0);
        y1 = __builtin_amdgcn_mfma_f32_16x16x32_bf16(Yhi[0], Blo[0], y1, 0, 0, 0);
        y1 = __builtin_amdgcn_mfma_f32_16x16x32_bf16(Yhi[1], Blo[1], y1, 0, 0, 0);
        f32x4 ys = y0 + y1;
        u16x4 pv;
#pragma unroll
        for (int r = 0; r < 4; r++){
            union { _Float16 h; unsigned short s; } c;
            c.h = (_Float16)ys[r];
            pv[r] = c.s;
        }
        *(u16x4*)(prey + (spy + (TLEN - 1)) * 64 + j0) = pv;
    }
}

// ---------------------------------------------------------------------------
extern "C" void kernel_launch(void* const* d_in, const int* in_sizes, int n_in,
                              void* d_out, int out_size, void* d_ws, size_t ws_size,
                              hipStream_t stream){
    (void)in_sizes; (void)n_in; (void)out_size; (void)ws_size;
    const float* x    = (const float*)d_in[0];
    const float* Wihx = (const float*)d_in[1];
    const float* Whhx = (const float*)d_in[2];
    const float* bihx = (const float*)d_in[3];
    const float* bhhx = (const float*)d_in[4];
    const float* Wihy = (const float*)d_in[5];
    const float* Whhy = (const float*)d_in[6];
    const float* bihy = (const float*)d_in[7];
    const float* bhhy = (const float*)d_in[8];
    _Float16* prex = (_Float16*)d_ws;                          // 33.5MB
    _Float16* prey = prex + (size_t)NSEQ * TLEN * 64;          // 33.5MB
    float* of = (float*)d_out;

    k_proj0 <<<2048, 256, 0, stream>>>(x, Wihx, bihx, bhhx, prex);
    k_scan<0><<<64, 512, 0, stream>>>(prex, Whhx, Wihy, bihy, bhhy, prey, nullptr);
    k_scan<1><<<64, 512, 0, stream>>>(prey, Whhy, nullptr, nullptr, nullptr, nullptr, of);
}

// Round 6
// 232.836 us; speedup vs baseline: 1.5199x; 1.4246x over previous
//
#include <hip/hip_runtime.h>
#include <stdint.h>

// B=16, C=64, H=128, W=128, HX=HY=64. All I/O fp32.
// Pipeline (3 kernels):
//   k_proj0 : pre_x[t=w][seq=(b,h)][j] (f16, incl bias) = Wihx·x + b   (bf16 hi/lo, unchanged)
//   k_scan<0>: X recurrence; FUSED Y-projection -> pre_y[t=h][seq=(b,w)][j] (f16, incl bias)
//   k_scan<1>: Y recurrence -> out[b][j][h][w] fp32
// d_ws: pre_x (33.5MB) + pre_y (33.5MB) = 67MB.
// ROUND 6: F16-DIRECT SCAN. Empirical tick law (rounds 0/2/4):
//   tick ~= 200ns fixed + ~26ns per MFMA issued per wave.
// All occupancy attacks failed (rounds 1/3/5: allocator pins 512-thr blocks
// to ~100 VGPR -> spills; round 2/4: intra-wave/BLOCK dual chain doubles the
// work term). So: cut the work term. h lives in (-1,1) => fp16 carries it
// with 2^-12 abs error, BELOW the existing f16 'pre' storage error (~2^-10)
// that dominates the measured absmax. Direct f16 MFMA kills the bf16 hi/lo
// split: PASS0 12->4 MFMA/step, PASS1 6->2, plus all partial-sum/pack VALU
// and half the LDS traffic. k_proj0 keeps bf16 hi/lo (error anchor).

#define TLEN 128
#define NSEQ 2048
#define PSH (NSEQ*64)   // f16 elems per t-slice
#define GT 16           // steps per group

typedef __bf16   bf16x8 __attribute__((ext_vector_type(8)));
typedef _Float16 f16x8  __attribute__((ext_vector_type(8)));
typedef _Float16 f16x4  __attribute__((ext_vector_type(4)));
typedef float    f32x4  __attribute__((ext_vector_type(4)));
typedef unsigned short u16x4 __attribute__((ext_vector_type(4)));

static __device__ __forceinline__ unsigned int fbits(float f){
    union { float f; unsigned int u; } v; v.f = f; return v.u;
}
static __device__ __forceinline__ float ubits(unsigned int u){
    union { unsigned int u; float f; } v; v.u = u; return v.f;
}
static __device__ __forceinline__ float bf2f(unsigned short s){ return ubits(((unsigned int)s) << 16); }
static __device__ __forceinline__ unsigned short f2bf(float f){
    unsigned int u = fbits(f);
    return (unsigned short)((u + 0x7FFFu + ((u >> 16) & 1u)) >> 16);
}
static __device__ __forceinline__ __bf16 us2b(unsigned short s){
    union { unsigned short u; __bf16 b; } v; v.u = s; return v.b;
}
static __device__ __forceinline__ unsigned short h2us(_Float16 h){
    union { _Float16 h; unsigned short s; } v; v.h = h; return v.s;
}
struct bfpair { __bf16 hi, lo; };
static __device__ __forceinline__ bfpair splitf(float f){   // RNE split (weights, once)
    unsigned short h = f2bf(f);
    bfpair r; r.hi = us2b(h); r.lo = us2b(f2bf(f - bf2f(h))); return r;
}
static __device__ __forceinline__ float fast_tanh(float x){
    float e = __builtin_amdgcn_exp2f(x * 2.8853900817779268f);
    return 1.0f - 2.0f * __builtin_amdgcn_rcpf(e + 1.0f);
}

// ---------------------------------------------------------------------------
// k_proj0: pre_x[w][b*128+h][j] = f16( sum_c x[b][c][h][w]*Wihx[j][c] + bias )
// bf16 hi/lo 3-term MFMA. Block 256thr/4 waves; wave: 32 rows x 64 j.
__global__ __launch_bounds__(256) void k_proj0(const float* __restrict__ A,
                                               const float* __restrict__ Wih,
                                               const float* __restrict__ b1,
                                               const float* __restrict__ b2,
                                               _Float16* __restrict__ pre){
    int lane = threadIdx.x & 63;
    int wv   = threadIdx.x >> 6;
    int q    = lane >> 4, l15 = lane & 15;

    bf16x8 Whi[4][2], Wlo[4][2];
#pragma unroll
    for (int n = 0; n < 4; n++)
#pragma unroll
        for (int kc = 0; kc < 2; kc++){
            const float* p = Wih + (n * 16 + l15) * 64 + kc * 32 + q * 8;
#pragma unroll
            for (int i = 0; i < 8; i++){
                bfpair s = splitf(p[i]);
                Whi[n][kc][i] = s.hi; Wlo[n][kc][i] = s.lo;
            }
        }
    float bias[4];
#pragma unroll
    for (int n = 0; n < 4; n++){
        int j = n * 16 + l15;
        bias[n] = b1[j] + b2[j];
    }

    int row0 = blockIdx.x * 128 + wv * 32;

    float av[2][2][8];
#pragma unroll
    for (int mi = 0; mi < 2; mi++){
        int r = row0 + mi * 16 + l15;
        int b = r >> 14, hw = r & 16383;
        const float* xb = A + (size_t)b * 1048576 + hw;
#pragma unroll
        for (int kc = 0; kc < 2; kc++)
#pragma unroll
            for (int i = 0; i < 8; i++)
                av[mi][kc][i] = xb[(size_t)(kc * 32 + q * 8 + i) * 16384];
    }

#pragma unroll
    for (int mi = 0; mi < 2; mi++){
        int rb = row0 + mi * 16;
        bf16x8 Ahi[2], Alo[2];
#pragma unroll
        for (int kc = 0; kc < 2; kc++)
#pragma unroll
            for (int i = 0; i < 8; i++){
                bfpair s = splitf(av[mi][kc][i]);
                Ahi[kc][i] = s.hi; Alo[kc][i] = s.lo;
            }
        f32x4 acc[4];
#pragma unroll
        for (int n = 0; n < 4; n++) acc[n] = (f32x4){bias[n], bias[n], bias[n], bias[n]};
#pragma unroll
        for (int n = 0; n < 4; n++)
#pragma unroll
            for (int kc = 0; kc < 2; kc++){
                acc[n] = __builtin_amdgcn_mfma_f32_16x16x32_bf16(Ahi[kc], Whi[n][kc], acc[n], 0, 0, 0);
                acc[n] = __builtin_amdgcn_mfma_f32_16x16x32_bf16(Alo[kc], Whi[n][kc], acc[n], 0, 0, 0);
                acc[n] = __builtin_amdgcn_mfma_f32_16x16x32_bf16(Ahi[kc], Wlo[n][kc], acc[n], 0, 0, 0);
            }
        // rows rb..rb+15 share (b,h); w = (rb&127) + q*4 + rr. seq_x = b*128+h.
        int bT = rb >> 14, hT = (rb >> 7) & 127, wBase = rb & 127;
        size_t seqOff = (size_t)bT * 128 + hT;
#pragma unroll
        for (int n = 0; n < 4; n++)
#pragma unroll
            for (int rr = 0; rr < 4; rr++){
                int w = wBase + q * 4 + rr;
                pre[((size_t)w * NSEQ + seqOff) * 64 + n * 16 + l15] = (_Float16)acc[n][rr];
            }
    }
}

// ---------------------------------------------------------------------------
// k_scan<PASS>: h_t = tanh(pre_t + Whh h_{t-1}), 128 blocks x 4 waves.
// Wave wv owns j-tile [wv*16,+16). Whh (and Wy) held as f16 A-frags in VGPRs.
// h carried as f16 (h in (-1,1): 2^-12 abs error, below the pre-f16 error
// floor). Per step: 2 MFMA recurrence (+2 MFMA Y-proj in PASS0) -- down from
// 6 (+6) with bf16 hi/lo -- no partial-sum adds, no hi/lo packing, single
// u16 LDS plane (half the LDS traffic of the hi/lo scheme).
// h exchanged via swizzled LDS (parity dbuf) + one __syncthreads per step.
// pre slab (16 steps) loaded into registers at group top; outputs staged in
// registers, burst-stored at group end -> barriers stay vmcnt-clean.
// PASS 0: fused Y-proj on B-frags (h_{t-1}) -> pre_y[t-1] f16 (incl bias_y).
// PASS 1: final out[b][j][t][w] fp32.
template<int PASS>
__global__ __launch_bounds__(256) void k_scan(const _Float16* __restrict__ pre,
                                              const float* __restrict__ Whh,
                                              const float* __restrict__ Wy,
                                              const float* __restrict__ by1,
                                              const float* __restrict__ by2,
                                              _Float16* __restrict__ prey,
                                              float* __restrict__ outf){
    __shared__ alignas(16) unsigned short hbuf[2][16][64];  // [par][seq][j] f16 bits
    int lane = threadIdx.x & 63;
    int wv   = threadIdx.x >> 6;
    int q = lane >> 4, l15 = lane & 15;
    int n0 = blockIdx.x * 16;
    int j0 = wv * 16 + q * 4;

    f16x8 Af[2];
#pragma unroll
    for (int kc = 0; kc < 2; kc++){
        const float* p = Whh + (wv * 16 + l15) * 64 + kc * 32 + q * 8;
#pragma unroll
        for (int i = 0; i < 8; i++)
            Af[kc][i] = (_Float16)p[i];
    }
    f16x8 Yf[2];
    f32x4 biasy = (f32x4){0.f, 0.f, 0.f, 0.f};
    if constexpr (PASS == 0){
#pragma unroll
        for (int kc = 0; kc < 2; kc++){
            const float* p = Wy + (wv * 16 + l15) * 64 + kc * 32 + q * 8;
#pragma unroll
            for (int i = 0; i < 8; i++)
                Yf[kc][i] = (_Float16)p[i];
        }
#pragma unroll
        for (int r = 0; r < 4; r++) biasy[r] = by1[j0 + r] + by2[j0 + r];
    }

    f16x8 Bf[2];
#pragma unroll
    for (int kc = 0; kc < 2; kc++)
#pragma unroll
        for (int i = 0; i < 8; i++) Bf[kc][i] = (_Float16)0.f;

    int bb = n0 >> 7, low7 = n0 & 127;   // PASS0: h0 = low7; PASS1: w0 = low7

    const _Float16* pb = pre + (size_t)(n0 + l15) * 64 + j0;
    size_t spy = (size_t)(low7 + l15) * NSEQ + (size_t)bb * 128;  // PASS0 prey seq base

    int e   = l15 & 7;
    int wj  = (((j0 >> 3) ^ e) << 3) | (j0 & 7);
    int rj0 = ((q)     ^ e) << 3;
    int rj1 = ((4 + q) ^ e) << 3;

    f16x4 ps[GT];
    u16x4 prey_st[GT];
    f32x4 outst[GT];

    for (int g = 0; g < TLEN / GT; g++){
        int G = g * GT;
#pragma unroll
        for (int u = 0; u < GT; u++)
            ps[u] = *(const f16x4*)(pb + (size_t)(G + u) * PSH);

#pragma unroll
        for (int u = 0; u < GT; u++){
            int t = G + u;
            // ---- recurrence: 2 chained f16 MFMAs (critical path)
            f32x4 a = (f32x4){(float)ps[u][0], (float)ps[u][1], (float)ps[u][2], (float)ps[u][3]};
            a = __builtin_amdgcn_mfma_f32_16x16x32_f16(Af[0], Bf[0], a, 0, 0, 0);
            a = __builtin_amdgcn_mfma_f32_16x16x32_f16(Af[1], Bf[1], a, 0, 0, 0);
            // ---- fused Y-proj on current B (= h_{t-1}) -> pre_y[t-1];
            //      independent of the a-chain, fills its latency window
            if constexpr (PASS == 0){
                f32x4 y = biasy;
                y = __builtin_amdgcn_mfma_f32_16x16x32_f16(Yf[0], Bf[0], y, 0, 0, 0);
                y = __builtin_amdgcn_mfma_f32_16x16x32_f16(Yf[1], Bf[1], y, 0, 0, 0);
#pragma unroll
                for (int r = 0; r < 4; r++)
                    prey_st[u][r] = h2us((_Float16)y[r]);
            }

            u16x4 h4;
#pragma unroll
            for (int r = 0; r < 4; r++){
                float tv = fast_tanh(a[r]);
                if constexpr (PASS == 1) outst[u][r] = tv;
                h4[r] = h2us((_Float16)tv);
            }
            int par = t & 1;
            *(u16x4*)&hbuf[par][l15][wj] = h4;
            __syncthreads();
            Bf[0] = *(const f16x8*)&hbuf[par][l15][rj0];
            Bf[1] = *(const f16x8*)&hbuf[par][l15][rj1];
        }
        // ---- burst stores (drained once at next group's first barrier)
        if constexpr (PASS == 0){
#pragma unroll
            for (int u = 0; u < GT; u++){
                int tp = G - 1 + u;
                if (tp >= 0)
                    *(u16x4*)(prey + (spy + tp) * 64 + j0) = prey_st[u];
            }
        } else {
#pragma unroll
            for (int u = 0; u < GT; u++)
#pragma unroll
                for (int r = 0; r < 4; r++)
                    outf[((size_t)(bb * 64 + j0 + r) * TLEN + (G + u)) * 128 + low7 + l15] = outst[u][r];
        }
    }
    // tail: pre_y[127] from final B (= h_127)
    if constexpr (PASS == 0){
        f32x4 y = biasy;
        y = __builtin_amdgcn_mfma_f32_16x16x32_f16(Yf[0], Bf[0], y, 0, 0, 0);
        y = __builtin_amdgcn_mfma_f32_16x16x32_f16(Yf[1], Bf[1], y, 0, 0, 0);
        u16x4 pv;
#pragma unroll
        for (int r = 0; r < 4; r++)
            pv[r] = h2us((_Float16)y[r]);
        *(u16x4*)(prey + (spy + (TLEN - 1)) * 64 + j0) = pv;
    }
}

// ---------------------------------------------------------------------------
extern "C" void kernel_launch(void* const* d_in, const int* in_sizes, int n_in,
                              void* d_out, int out_size, void* d_ws, size_t ws_size,
                              hipStream_t stream){
    (void)in_sizes; (void)n_in; (void)out_size; (void)ws_size;
    const float* x    = (const float*)d_in[0];
    const float* Wihx = (const float*)d_in[1];
    const float* Whhx = (const float*)d_in[2];
    const float* bihx = (const float*)d_in[3];
    const float* bhhx = (const float*)d_in[4];
    const float* Wihy = (const float*)d_in[5];
    const float* Whhy = (const float*)d_in[6];
    const float* bihy = (const float*)d_in[7];
    const float* bhhy = (const float*)d_in[8];
    _Float16* prex = (_Float16*)d_ws;                          // 33.5MB
    _Float16* prey = prex + (size_t)NSEQ * TLEN * 64;          // 33.5MB
    float* of = (float*)d_out;

    k_proj0 <<<2048, 256, 0, stream>>>(x, Wihx, bihx, bhhx, prex);
    k_scan<0><<<128, 256, 0, stream>>>(prex, Whhx, Wihy, bihy, bhhy, prey, nullptr);
    k_scan<1><<<128, 256, 0, stream>>>(prey, Whhy, nullptr, nullptr, nullptr, nullptr, of);
}